// Round 1
// baseline (465.406 us; speedup 1.0000x reference)
//
#include <hip/hip_runtime.h>
#include <hip/hip_bf16.h>

#define MPTS 50000
#define NPTS 100000
#define HH 32
#define KK 15
#define CC 64
#define TM 16   // queries per block; 50000 = 16*3125 exactly

// LDS budget: q 192 + kp 180 + idx 2048 + w 16K + weighted 30K + union 16K ~ 64.4 KB -> 2 blocks/CU
union UShared {
    float feats[HH][68];      // phase B: one query's gathered feats, row pad 68 (272B, 16B-aligned)
    float red[4][TM][64];     // phase C: partial-sum reduction across the 4 kc-quarters
};

__global__ __launch_bounds__(256, 2) void kpconv_kernel(
    const float* __restrict__ q_points,   // (M,3)
    const float* __restrict__ s_points,   // (N,3)
    const float* __restrict__ s_feats,    // (N,64)
    const int*   __restrict__ nbr,        // (M,32) int32
    const float* __restrict__ weights,    // (15,64,64) [k][c][d]
    const float* __restrict__ kpts,       // (15,3)
    float* __restrict__ out)              // (M,64)
{
    const int t  = threadIdx.x;
    const int m0 = blockIdx.x * TM;

    __shared__ float q_lds[TM][3];
    __shared__ float kp_lds[KK][3];
    __shared__ int   idx_lds[TM][HH];
    __shared__ __hip_bfloat16 w_lds[TM][16][HH];                 // [m][k][h], k padded to 16
    __shared__ __align__(16) __hip_bfloat16 weighted_lds[TM][960]; // [m][k*64+c], bf16
    __shared__ float invcnt[TM];
    __shared__ __align__(16) UShared u;

    // ---------------- Phase A: load small tensors, compute kernel weights ----------------
    for (int i = t; i < TM * 3; i += 256) q_lds[i / 3][i % 3] = q_points[m0 * 3 + i];
    if (t < KK * 3) kp_lds[t / 3][t % 3] = kpts[t];
    for (int i = t; i < TM * HH; i += 256) idx_lds[i >> 5][i & 31] = nbr[m0 * HH + i];
    __syncthreads();

    for (int p = t; p < TM * HH; p += 256) {
        const int m = p >> 5, h = p & 31;
        const int idx = idx_lds[m][h];
        float px, py, pz;
        if (idx < NPTS) {
            px = s_points[idx * 3 + 0];
            py = s_points[idx * 3 + 1];
            pz = s_points[idx * 3 + 2];
        } else {                       // padding shadow point at INF=1e6
            px = py = pz = 1.0e6f;
        }
        const float rx = px - q_lds[m][0];
        const float ry = py - q_lds[m][1];
        const float rz = pz - q_lds[m][2];
#pragma unroll
        for (int k = 0; k < KK; k++) {
            const float dx = rx - kp_lds[k][0];
            const float dy = ry - kp_lds[k][1];
            const float dz = rz - kp_lds[k][2];
            const float d2 = dx * dx + dy * dy + dz * dz;
            float w = 1.0f - sqrtf(d2) * 0.5f;   // SIGMA = 2.0
            w = fmaxf(w, 0.0f);
            w_lds[m][k][h] = __float2bfloat16(w);
        }
        w_lds[m][15][h] = __float2bfloat16(0.0f);   // pad row
    }
    // (first barrier of phase B loop makes w_lds/idx visible)

    // ---------------- Phase B: per-query gather + weighted[k][c] ----------------
    const int kg = t >> 4;            // 0..15 (15 idle)
    const int c4 = (t & 15) * 4;      // channel quad
    for (int m = 0; m < TM; m++) {
        __syncthreads();              // prev iter done reading u.feats (and m=0: w_lds visible)
#pragma unroll
        for (int sIt = 0; sIt < 2; sIt++) {
            const int s = sIt * 256 + t;           // 512 float4 slots
            const int h = s >> 4, cc4 = (s & 15) * 4;
            const int idx = idx_lds[m][h];
            float4 f;
            if (idx < NPTS) f = *(const float4*)&s_feats[idx * 64 + cc4];
            else            f = make_float4(0.f, 0.f, 0.f, 0.f);
            *(float4*)&u.feats[h][cc4] = f;
        }
        __syncthreads();

        // neighbor count: replicate numpy float32 pairwise-8 sum order, then (sum > 0)
        if (t < 32) {
            float r[8];
#pragma unroll
            for (int j = 0; j < 8; j++) r[j] = u.feats[t][j];
            for (int i = 8; i < 64; i += 8) {
#pragma unroll
                for (int j = 0; j < 8; j++) r[j] += u.feats[t][i + j];
            }
            const float s = ((r[0] + r[1]) + (r[2] + r[3])) + ((r[4] + r[5]) + (r[6] + r[7]));
            const unsigned long long b = __ballot(s > 0.0f);
            const int cnt = __popcll(b);
            if (t == 0) invcnt[m] = 1.0f / (float)(cnt < 1 ? 1 : cnt);
        }

        if (kg < KK) {
            float a0 = 0.f, a1 = 0.f, a2 = 0.f, a3 = 0.f;
#pragma unroll
            for (int h = 0; h < HH; h++) {
                const float4 f = *(const float4*)&u.feats[h][c4];
                const float wv = __bfloat162float(w_lds[m][kg][h]);   // wave-uniform broadcast
                a0 += wv * f.x; a1 += wv * f.y; a2 += wv * f.z; a3 += wv * f.w;
            }
            const int base = kg * 64 + c4;
            weighted_lds[m][base + 0] = __float2bfloat16(a0);
            weighted_lds[m][base + 1] = __float2bfloat16(a1);
            weighted_lds[m][base + 2] = __float2bfloat16(a2);
            weighted_lds[m][base + 3] = __float2bfloat16(a3);
        }
    }
    __syncthreads();   // weighted_lds + invcnt visible; u.feats reads done -> u.red safe

    // ---------------- Phase C: out[m][d] = sum_kc weighted[m][kc] * W[kc][d] ----------------
    {
        const int d = t & 63;
        const int q = t >> 6;                 // 4-way split over kc
        float acc[TM];
#pragma unroll
        for (int m = 0; m < TM; m++) acc[m] = 0.0f;
        for (int kc = q * 240; kc < q * 240 + 240; kc += 4) {
            const float* wp = &weights[kc * 64 + d];   // coalesced over d, L2-resident
            const float w0 = wp[0];
            const float w1 = wp[64];
            const float w2 = wp[128];
            const float w3 = wp[192];
#pragma unroll
            for (int m = 0; m < TM; m++) {
                const ushort4 pv = *(const ushort4*)&weighted_lds[m][kc];  // wave-uniform b64
                const float p0 = __uint_as_float((unsigned)pv.x << 16);
                const float p1 = __uint_as_float((unsigned)pv.y << 16);
                const float p2 = __uint_as_float((unsigned)pv.z << 16);
                const float p3 = __uint_as_float((unsigned)pv.w << 16);
                acc[m] += p0 * w0 + p1 * w1 + p2 * w2 + p3 * w3;
            }
        }
#pragma unroll
        for (int m = 0; m < TM; m++) u.red[q][m][d] = acc[m];
    }
    __syncthreads();

    for (int o = t; o < TM * 64; o += 256) {
        const int m = o >> 6, dd = o & 63;
        const float s = (u.red[0][m][dd] + u.red[1][m][dd]) + (u.red[2][m][dd] + u.red[3][m][dd]);
        out[(m0 + m) * 64 + dd] = s * invcnt[m];
    }
}

extern "C" void kernel_launch(void* const* d_in, const int* in_sizes, int n_in,
                              void* d_out, int out_size, void* d_ws, size_t ws_size,
                              hipStream_t stream) {
    const float* q_points = (const float*)d_in[0];
    const float* s_points = (const float*)d_in[1];
    const float* s_feats  = (const float*)d_in[2];
    const int*   nbr      = (const int*)d_in[3];
    const float* weights  = (const float*)d_in[4];
    const float* kpts     = (const float*)d_in[5];
    float* out = (float*)d_out;

    kpconv_kernel<<<MPTS / TM, 256, 0, stream>>>(q_points, s_points, s_feats, nbr,
                                                 weights, kpts, out);
}

// Round 2
// 240.114 us; speedup vs baseline: 1.9383x; 1.9383x over previous
//
#include <hip/hip_runtime.h>
#include <hip/hip_bf16.h>

#define MPTS 50000
#define NPTS 100000
#define HH 32
#define KK 15
#define CC 64
#define TM 16          // queries per block; 50000 = 16*3125
#define KC 1024        // phase-C K dim: 64 c * 16 k (k=15 is zero pad)
#define WTP 1032       // wt_lds row stride (shorts): 1032*2=2064 B, 16B-aligned, banks offset 4/row
#define FBP 40         // fb_lds h-stride (shorts): 80 B rows
#define F32P 68        // f32 stage c-stride (floats): 272 B rows

typedef __attribute__((ext_vector_type(8))) short short8;
typedef __attribute__((ext_vector_type(4))) float floatx4;

static __device__ __forceinline__ unsigned short f2bf(float f) {
    __hip_bfloat16 h = __float2bfloat16(f);
    return *reinterpret_cast<unsigned short*>(&h);
}

// ---- prep: W''[d][c*16+k] = bf16(weights[k][c][d]), k=15 row zeroed. 64x1024 bf16 = 128 KB in d_ws
__global__ void prep_weights(const float* __restrict__ w, unsigned short* __restrict__ wbf) {
    const int i = blockIdx.x * 256 + threadIdx.x;       // 65536
    const int d = i >> 10, kc = i & (KC - 1);
    const int c = kc >> 4, k = kc & 15;
    const float v = (k < KK) ? w[k * 4096 + c * 64 + d] : 0.0f;
    wbf[i] = f2bf(v);
}

__global__ __launch_bounds__(256, 2) void kpconv_kernel(
    const float* __restrict__ q_points,   // (M,3)
    const float* __restrict__ s_points,   // (N,3)
    const float* __restrict__ s_feats,    // (N,64)
    const int*   __restrict__ nbr,        // (M,32)
    const unsigned short* __restrict__ wbf, // W'' (64,1024) bf16
    const float* __restrict__ kpts,       // (15,3)
    float* __restrict__ out)              // (M,64)
{
    const int t    = threadIdx.x;
    const int m0   = blockIdx.x * TM;
    const int lane = t & 63;
    const int wv   = t >> 6;          // wave id = c-tile (B) / d-tile (C)
    const int l15  = lane & 15;
    const int lq   = lane >> 4;       // quad 0..3

    __shared__ float q_lds[TM][3];
    __shared__ float kp_lds[KK][4];
    __shared__ int   idx_lds[TM][HH];
    __shared__ __align__(16) __hip_bfloat16 w_lds[TM][16][HH];      // A-op phase B, 16 KB
    __shared__ __align__(16) float f32_lds[2][HH][F32P];            // fp32 gather stage, 17 KB
    __shared__ __align__(16) __hip_bfloat16 fb_lds[CC][FBP];        // B-op phase B [c][h], 5 KB
    __shared__ __align__(16) __hip_bfloat16 wt_lds[TM][WTP];        // weighted [m][c*16+k], 32.25 KB
    __shared__ float invcnt[TM];

    // ---------------- Phase A: small loads ----------------
    if (t < TM * 3) q_lds[t / 3][t % 3] = q_points[m0 * 3 + t];
    if (t < KK * 3) kp_lds[t / 3][t % 3] = kpts[t];
    idx_lds[t >> 5][t & 31]           = nbr[m0 * HH + t];
    idx_lds[(t + 256) >> 5][t & 31]   = nbr[m0 * HH + t + 256];
    __syncthreads();

    // -------- prologue: issue feats gather for m=0 (2 float4/thread, coalesced 16 lanes/row)
    float4 g0, g1;
    {
        const int l0 = t, l1 = t + 256;
        const int i0 = idx_lds[0][l0 >> 4], i1 = idx_lds[0][l1 >> 4];
        g0 = (i0 < NPTS) ? *(const float4*)&s_feats[i0 * 64 + (l0 & 15) * 4]
                         : make_float4(0.f, 0.f, 0.f, 0.f);
        g1 = (i1 < NPTS) ? *(const float4*)&s_feats[i1 * 64 + (l1 & 15) * 4]
                         : make_float4(0.f, 0.f, 0.f, 0.f);
    }

    // -------- Phase A2: kernel-point weights w_lds[m][k][h] (bf16), k=15 zero pad
#pragma unroll
    for (int s = 0; s < 2; s++) {
        const int it = s * 256 + t;
        const int m = it >> 5, h = it & 31;
        const int idx = idx_lds[m][h];
        float px = 1.0e6f, py = 1.0e6f, pz = 1.0e6f;
        if (idx < NPTS) {
            px = s_points[idx * 3 + 0];
            py = s_points[idx * 3 + 1];
            pz = s_points[idx * 3 + 2];
        }
        const float rx = px - q_lds[m][0];
        const float ry = py - q_lds[m][1];
        const float rz = pz - q_lds[m][2];
#pragma unroll
        for (int k = 0; k < KK; k++) {
            const float dx = rx - kp_lds[k][0];
            const float dy = ry - kp_lds[k][1];
            const float dz = rz - kp_lds[k][2];
            const float d2 = dx * dx + dy * dy + dz * dz;
            float w = fmaxf(1.0f - sqrtf(d2) * 0.5f, 0.0f);
            w_lds[m][k][h] = __float2bfloat16(w);
        }
        w_lds[m][15][h] = __float2bfloat16(0.0f);
    }
    // write prologue gather to f32 buf 0
    {
        const int l0 = t, l1 = t + 256;
        *(float4*)&f32_lds[0][l0 >> 4][(l0 & 15) * 4] = g0;
        *(float4*)&f32_lds[0][l1 >> 4][(l1 & 15) * 4] = g1;
    }

    // ---------------- m-loop: gather-prefetch | count | transpose | MFMA-B ----------------
    for (int m = 0; m < TM; m++) {
        __syncthreads();   // f32[m&1] + (m==0: w_lds) ready; fb_lds free
        const int mb = m & 1;

        // issue gather for m+1
        if (m < TM - 1) {
            const int l0 = t, l1 = t + 256;
            const int i0 = idx_lds[m + 1][l0 >> 4], i1 = idx_lds[m + 1][l1 >> 4];
            g0 = (i0 < NPTS) ? *(const float4*)&s_feats[i0 * 64 + (l0 & 15) * 4]
                             : make_float4(0.f, 0.f, 0.f, 0.f);
            g1 = (i1 < NPTS) ? *(const float4*)&s_feats[i1 * 64 + (l1 & 15) * 4]
                             : make_float4(0.f, 0.f, 0.f, 0.f);
        }

        // count: exact numpy pairwise order over 64 channels (lane = h)
        if (t < 32) {
            const float* row = &f32_lds[mb][t][0];
            float r[8];
#pragma unroll
            for (int j = 0; j < 8; j++) r[j] = row[j];
#pragma unroll
            for (int i = 8; i < 64; i += 8)
#pragma unroll
                for (int j = 0; j < 8; j++) r[j] += row[i + j];
            const float s = ((r[0] + r[1]) + (r[2] + r[3])) + ((r[4] + r[5]) + (r[6] + r[7]));
            const unsigned long long b = __ballot(s > 0.0f);
            const int cnt = __popcll(b);
            if (t == 0) invcnt[m] = 1.0f / (float)(cnt < 1 ? 1 : cnt);
        }

        // transpose + cvt: f32 [h][c] -> bf16 fb_lds[c][h]  (thread: c = t>>2, h-octet = t&3)
        {
            const int c = t >> 2, ho = (t & 3) * 8;
            uint4 pk;
            unsigned p[8];
#pragma unroll
            for (int j = 0; j < 8; j++) p[j] = f2bf(f32_lds[mb][ho + j][c]);
            pk.x = p[0] | (p[1] << 16);
            pk.y = p[2] | (p[3] << 16);
            pk.z = p[4] | (p[5] << 16);
            pk.w = p[6] | (p[7] << 16);
            *(uint4*)&fb_lds[c][ho] = pk;
        }

        // write prefetched gather (m+1) into the other f32 buffer
        if (m < TM - 1) {
            const int l0 = t, l1 = t + 256;
            *(float4*)&f32_lds[mb ^ 1][l0 >> 4][(l0 & 15) * 4] = g0;
            *(float4*)&f32_lds[mb ^ 1][l1 >> 4][(l1 & 15) * 4] = g1;
        }
        __syncthreads();   // fb_lds ready

        // MFMA phase B: D1[k][c-tile wv] = sum_h w[k][h] * f[h][c]
        {
            const short8 a = *(const short8*)&w_lds[m][l15][lq * 8];
            const short8 b = *(const short8*)&fb_lds[wv * 16 + l15][lq * 8];
            floatx4 d = {0.f, 0.f, 0.f, 0.f};
            d = __builtin_amdgcn_mfma_f32_16x16x32_bf16(a, b, d, 0, 0, 0);
            const int c = wv * 16 + l15;     // D col
            const int k0 = lq * 4;           // D rows k0..k0+3
            ushort4 pk;
            pk.x = f2bf(d[0]); pk.y = f2bf(d[1]); pk.z = f2bf(d[2]); pk.w = f2bf(d[3]);
            *(ushort4*)&wt_lds[m][c * 16 + k0] = pk;
        }
    }
    __syncthreads();   // wt_lds + invcnt ready

    // ---------------- Phase C: out[m][d] = sum_kc wt[m][kc] * W''[kc][d] ----------------
    {
        floatx4 acc = {0.f, 0.f, 0.f, 0.f};
        const __hip_bfloat16* ap = &wt_lds[l15][lq * 8];
        const unsigned short* bp = wbf + (wv * 16 + l15) * KC + lq * 8;
#pragma unroll 8
        for (int s = 0; s < KC / 32; s++) {
            const short8 a = *(const short8*)(ap + s * 32);
            const short8 b = *(const short8*)(bp + s * 32);
            acc = __builtin_amdgcn_mfma_f32_16x16x32_bf16(a, b, acc, 0, 0, 0);
        }
        const int d = wv * 16 + l15;
#pragma unroll
        for (int r = 0; r < 4; r++) {
            const int m = lq * 4 + r;
            out[(m0 + m) * 64 + d] = acc[r] * invcnt[m];
        }
    }
}

extern "C" void kernel_launch(void* const* d_in, const int* in_sizes, int n_in,
                              void* d_out, int out_size, void* d_ws, size_t ws_size,
                              hipStream_t stream) {
    const float* q_points = (const float*)d_in[0];
    const float* s_points = (const float*)d_in[1];
    const float* s_feats  = (const float*)d_in[2];
    const int*   nbr      = (const int*)d_in[3];
    const float* weights  = (const float*)d_in[4];
    const float* kpts     = (const float*)d_in[5];
    float* out = (float*)d_out;
    unsigned short* wbf = (unsigned short*)d_ws;   // 64*1024*2 = 128 KB

    prep_weights<<<CC * KC / 256, 256, 0, stream>>>(weights, wbf);
    kpconv_kernel<<<MPTS / TM, 256, 0, stream>>>(q_points, s_points, s_feats, nbr,
                                                 wbf, kpts, out);
}